// Round 3
// baseline (227.984 us; speedup 1.0000x reference)
//
#include <hip/hip_runtime.h>

// RGCN restructured:
//   out1 = A @ W1,   A[i, r*N+j] = adj[r,i,j]   (6144 x 12288) @ (12288 x 256)
//   out2 = A @ Y,    Y[r*N+j, h] = (relu(out1) @ W2_r)[j,h]
//   final[h] = sum_i out1[i,h] ; final[256+h] = sum_i out2[i,h]
// Big GEMMs: bf16 MFMA 16x16x32, split-K S=8, bf16 partials + fused reduce.
// GEMM structure: LDS double-buffer, 1 barrier/K-step, global_load_lds for B,
// 2-deep A register prefetch (T3 2-phase + T14 per the technique catalog).

#define NN 6144
#define HH 256
#define SPLIT 8
#define KCHUNK 1536   // (2*NN)/SPLIT
#define KSTEPS 24     // KCHUNK/64

typedef __attribute__((ext_vector_type(4))) float f32x4;
typedef __attribute__((ext_vector_type(8))) unsigned short u16x8;
typedef __attribute__((ext_vector_type(4))) unsigned short u16x4;

__device__ __forceinline__ unsigned short f2bf(float f) {
  unsigned int u = __float_as_uint(f);
  u += 0x7FFFu + ((u >> 16) & 1u);   // RNE
  return (unsigned short)(u >> 16);
}
__device__ __forceinline__ float bf2f(unsigned short h) {
  return __uint_as_float(((unsigned int)h) << 16);
}

__device__ __forceinline__ void mfma_bf16(f32x4& d, u16x8 a, u16x8 b) {
  asm("v_mfma_f32_16x16x32_bf16 %0, %1, %2, %0" : "+v"(d) : "v"(a), "v"(b));
}

// async global -> LDS, 16B per lane. LDS dest must be linear in lane (it is:
// our B stream is pre-swizzled in ws, staged as an identity copy).
__device__ __forceinline__ void gll16(const unsigned short* g, unsigned short* l) {
  __builtin_amdgcn_global_load_lds(
      (const __attribute__((address_space(1))) unsigned int*)g,
      (__attribute__((address_space(3))) unsigned int*)l,
      16, 0, 0);
}

// ---------------------------------------------------------------------------
// wgen: W_r[j,h] = c0*basis[0,j,h] + c1*basis[1,j,h], emitted transposed as
// 16B chunks: out[t*2048 + h*8 + sp] holds W[k = t*64 + (sp^(h&7))*8 + e][h]
// ---------------------------------------------------------------------------
__global__ void wgen_kernel(const float* __restrict__ basis,
                            const float* __restrict__ bc,
                            unsigned short* __restrict__ outw,
                            int tilesPerR, int jdim)
{
  __shared__ unsigned short wt[64][265];
  const int t  = blockIdx.x;
  const int r  = t / tilesPerR;
  const int jt = t % tilesPerR;
  const float c0 = bc[r * 2 + 0];
  const float c1 = bc[r * 2 + 1];
  const int tid = threadIdx.x;
  const float* b0 = basis + (size_t)jt * 64 * HH;
  const float* b1 = basis + (size_t)jdim * HH + (size_t)jt * 64 * HH;
#pragma unroll
  for (int k = 0; k < 16; ++k) {
    int idx = tid + k * 256;
    int row = idx >> 6;
    int c4  = (idx & 63) * 4;
    f32x4 v0 = *(const f32x4*)(b0 + (size_t)row * HH + c4);
    f32x4 v1 = *(const f32x4*)(b1 + (size_t)row * HH + c4);
    wt[row][c4 + 0] = f2bf(c0 * v0.x + c1 * v1.x);
    wt[row][c4 + 1] = f2bf(c0 * v0.y + c1 * v1.y);
    wt[row][c4 + 2] = f2bf(c0 * v0.z + c1 * v1.z);
    wt[row][c4 + 3] = f2bf(c0 * v0.w + c1 * v1.w);
  }
  __syncthreads();
#pragma unroll
  for (int k = 0; k < 8; ++k) {
    int chunk = tid + k * 256;
    int h  = chunk >> 3;
    int sp = chunk & 7;
    int j0 = (sp ^ (h & 7)) * 8;
    u16x8 v;
#pragma unroll
    for (int e = 0; e < 8; ++e) v[e] = wt[j0 + e][h];
    *(u16x8*)(outw + ((size_t)t * 2048 + chunk) * 8) = v;
  }
}

// ---------------------------------------------------------------------------
// Main GEMM: P_bf16[s] = A_chunk @ B_chunk  (BM=64, BN=256, BK=64)
// Double-buffered LDS, one __syncthreads per K-step.
//   iter kk (buf=cur): gll_lds B(kk+1)->cur^1 ; issue A regs(kk+2) ;
//                      MFMA on cur ; cvt+ds_write A(kk+1)->cur^1 ; barrier
// ---------------------------------------------------------------------------
__global__ __launch_bounds__(256, 2) void gemm_adj_kernel(
    const float* __restrict__ adj, const unsigned short* __restrict__ Bws,
    unsigned short* __restrict__ Pp)
{
  __shared__ __align__(16) unsigned short Alds[2][64 * 64];
  __shared__ __align__(16) unsigned short Blds[2][256 * 64];
  const int tid  = threadIdx.x;
  const int lane = tid & 63;
  const int wave = tid >> 6;
  const int mb = blockIdx.x;
  const int s  = blockIdx.y;
  const int i0 = mb * 64;
  const int kbase = s * KCHUNK;
  const int rrel  = kbase / NN;
  const int jb    = kbase % NN;
  const int tBase = kbase / 64;

  const int arow = tid >> 3;        // 0..31 (+32 for it=1)
  const int acol = (tid & 7) * 8;   // 0..56
  const float* aPtr = adj + (size_t)rrel * NN * NN
                      + (size_t)(i0 + arow) * NN + jb + acol;
  const unsigned short* bPtr = Bws + (size_t)tBase * 2048 * 8 + (size_t)tid * 8;

  f32x4 acc[4][4];
#pragma unroll
  for (int m = 0; m < 4; ++m)
#pragma unroll
    for (int n = 0; n < 4; ++n) acc[m][n] = (f32x4){0.f, 0.f, 0.f, 0.f};

  f32x4 av0[2][2], av1[2][2];   // two prefetch sets, [it][half]

#define ISSUE_A(SET, KK) do {                                                  \
    _Pragma("unroll")                                                          \
    for (int it = 0; it < 2; ++it) {                                           \
      SET[it][0] = *(const f32x4*)(aPtr + (size_t)it * 32 * NN + (KK) * 64);   \
      SET[it][1] = *(const f32x4*)(aPtr + (size_t)it * 32 * NN + (KK) * 64 + 4);\
    } } while (0)

#define ISSUE_B(BUF, KK) do {                                                  \
    _Pragma("unroll")                                                          \
    for (int c = 0; c < 8; ++c)                                                \
      gll16(bPtr + (size_t)(KK) * 2048 * 8 + c * 256 * 8,                      \
            (unsigned short*)((char*)Blds[BUF] + ((size_t)c * 256 + tid) * 16)); \
    } while (0)

#define STAGE_A(SET, BUF) do {                                                 \
    _Pragma("unroll")                                                          \
    for (int it = 0; it < 2; ++it) {                                           \
      int row = arow + it * 32;                                                \
      u16x8 w;                                                                 \
      w[0] = f2bf(SET[it][0].x); w[1] = f2bf(SET[it][0].y);                    \
      w[2] = f2bf(SET[it][0].z); w[3] = f2bf(SET[it][0].w);                    \
      w[4] = f2bf(SET[it][1].x); w[5] = f2bf(SET[it][1].y);                    \
      w[6] = f2bf(SET[it][1].z); w[7] = f2bf(SET[it][1].w);                    \
      *(u16x8*)((char*)Alds[BUF] + row * 128 +                                 \
                ((((tid & 7) ^ (row & 7))) << 4)) = w;                         \
    } } while (0)

#define COMPUTE(BUF) do {                                                      \
    _Pragma("unroll")                                                          \
    for (int ks = 0; ks < 2; ++ks) {                                           \
      u16x8 af[4], bfr[4];                                                     \
      _Pragma("unroll")                                                        \
      for (int m = 0; m < 4; ++m) {                                            \
        int row = m * 16 + (lane & 15);                                        \
        int off = (ks * 64 + ((lane >> 4) << 4)) ^ ((row & 7) << 4);           \
        af[m] = *(const u16x8*)((const char*)Alds[BUF] + row * 128 + off);     \
      }                                                                        \
      _Pragma("unroll")                                                        \
      for (int n = 0; n < 4; ++n) {                                            \
        int row = wave * 64 + n * 16 + (lane & 15);                            \
        int off = (ks * 64 + ((lane >> 4) << 4)) ^ ((row & 7) << 4);           \
        bfr[n] = *(const u16x8*)((const char*)Blds[BUF] + row * 128 + off);    \
      }                                                                        \
      _Pragma("unroll")                                                        \
      for (int m = 0; m < 4; ++m)                                              \
        _Pragma("unroll")                                                      \
        for (int n = 0; n < 4; ++n)                                            \
          mfma_bf16(acc[m][n], af[m], bfr[n]);                                 \
    } } while (0)

  // prologue: stage tile 0 into buf 0; preload A(0), A(1)
  ISSUE_B(0, 0);
  ISSUE_A(av0, 0);
  ISSUE_A(av1, 1);
  STAGE_A(av0, 0);
  __syncthreads();            // drains B(0) gll_lds too

  for (int kk = 0; kk < KSTEPS; kk += 2) {
    // ---- iter kk  (cur = 0) ----
    ISSUE_B(1, kk + 1);
    if (kk + 2 < KSTEPS) ISSUE_A(av0, kk + 2);
    COMPUTE(0);
    STAGE_A(av1, 1);          // A(kk+1): loaded 1.5 iters ago, covered
    __syncthreads();
    // ---- iter kk+1 (cur = 1) ----
    if (kk + 2 < KSTEPS) {
      ISSUE_B(0, kk + 2);
      if (kk + 3 < KSTEPS) ISSUE_A(av1, kk + 3);
    }
    COMPUTE(1);
    if (kk + 2 < KSTEPS) STAGE_A(av0, 0);
    __syncthreads();
  }
#undef ISSUE_A
#undef ISSUE_B
#undef STAGE_A
#undef COMPUTE

  // partials bf16: P[s][i][h]   (C/D: col=lane&15, row=(lane>>4)*4+q)
  unsigned short* P = Pp + ((size_t)s * NN + i0) * HH;
#pragma unroll
  for (int m = 0; m < 4; ++m)
#pragma unroll
    for (int n = 0; n < 4; ++n) {
      int col = wave * 64 + n * 16 + (lane & 15);
#pragma unroll
      for (int q = 0; q < 4; ++q) {
        int row = m * 16 + ((lane >> 4) << 2) + q;
        P[(size_t)row * HH + col] = f2bf(acc[m][n][q]);
      }
    }
}

// ---------------------------------------------------------------------------
// gemm_y: Y_r = x @ W2_r (K=256). Output written in B-operand layout.
// ---------------------------------------------------------------------------
__global__ __launch_bounds__(256, 2) void gemm_y_kernel(
    const unsigned short* __restrict__ xws, const unsigned short* __restrict__ w2ws,
    unsigned short* __restrict__ B2ws)
{
  __shared__ __align__(16) unsigned short Alds[64 * 64];
  __shared__ __align__(16) unsigned short Blds[256 * 64];
  const int tid  = threadIdx.x;
  const int lane = tid & 63;
  const int wave = tid >> 6;
  const int mb = blockIdx.x;
  const int r  = blockIdx.y;

  f32x4 acc[4][4];
#pragma unroll
  for (int m = 0; m < 4; ++m)
#pragma unroll
    for (int n = 0; n < 4; ++n) acc[m][n] = (f32x4){0.f, 0.f, 0.f, 0.f};

  for (int dt = 0; dt < 4; ++dt) {
    u16x8 avv[2];
    avv[0] = *(const u16x8*)(xws + (((size_t)(mb * 4 + dt)) * 512 + tid) * 8);
    avv[1] = *(const u16x8*)(xws + (((size_t)(mb * 4 + dt)) * 512 + 256 + tid) * 8);
    u16x8 bv[8];
#pragma unroll
    for (int c = 0; c < 8; ++c)
      bv[c] = *(const u16x8*)(w2ws + (((size_t)(r * 4 + dt)) * 2048 + c * 256 + tid) * 8);
    __syncthreads();
    *(u16x8*)(Alds + (size_t)tid * 8) = avv[0];
    *(u16x8*)(Alds + ((size_t)256 + tid) * 8) = avv[1];
#pragma unroll
    for (int c = 0; c < 8; ++c)
      *(u16x8*)(Blds + ((size_t)c * 256 + tid) * 8) = bv[c];
    __syncthreads();
#pragma unroll
    for (int ks = 0; ks < 2; ++ks) {
      u16x8 af[4], bfr[4];
#pragma unroll
      for (int m = 0; m < 4; ++m) {
        int row = m * 16 + (lane & 15);
        int off = (ks * 64 + ((lane >> 4) << 4)) ^ ((row & 7) << 4);
        af[m] = *(const u16x8*)((const char*)Alds + row * 128 + off);
      }
#pragma unroll
      for (int n = 0; n < 4; ++n) {
        int row = wave * 64 + n * 16 + (lane & 15);
        int off = (ks * 64 + ((lane >> 4) << 4)) ^ ((row & 7) << 4);
        bfr[n] = *(const u16x8*)((const char*)Blds + row * 128 + off);
      }
#pragma unroll
      for (int m = 0; m < 4; ++m)
#pragma unroll
        for (int n = 0; n < 4; ++n)
          mfma_bf16(acc[m][n], af[m], bfr[n]);
    }
  }
  // emit Y in B-operand layout: chunk(t=r*96+mb, h, pos) gets k-slot pos^(h&7)
  const int tg = r * 96 + mb;
#pragma unroll
  for (int m = 0; m < 4; ++m) {
    int scont = m * 2 + ((lane >> 4) >> 1);
    int e0    = ((lane >> 4) & 1) * 4;
#pragma unroll
    for (int n = 0; n < 4; ++n) {
      int h   = wave * 64 + n * 16 + (lane & 15);
      int pos = scont ^ (h & 7);
      u16x4 v;
      v[0] = f2bf(acc[m][n][0]); v[1] = f2bf(acc[m][n][1]);
      v[2] = f2bf(acc[m][n][2]); v[3] = f2bf(acc[m][n][3]);
      *(u16x4*)(B2ws + (((size_t)tg * 2048 + h * 8 + pos) * 8 + e0)) = v;
    }
  }
}

// ---------------------------------------------------------------------------
// reduce1: sum_s P[s] -> x = relu -> bf16 pre-swizzled A-tiles (xws)
//          + fused column-sum of out1 into fin[0..255]
// ---------------------------------------------------------------------------
__global__ void reduce1_kernel(const unsigned short* __restrict__ Pp,
                               unsigned short* __restrict__ xws,
                               float* __restrict__ fin)
{
  __shared__ float csm[8][256];
  const int tid = threadIdx.x;
  const int b   = blockIdx.x;
  const int hc  = tid & 31;
  const int rg  = tid >> 5;
  const int dt    = hc >> 3;
  const int scont = hc & 7;
  float cs[8] = {0.f, 0.f, 0.f, 0.f, 0.f, 0.f, 0.f, 0.f};
  for (int k = 0; k < 8; ++k) {
    int i = b * 64 + rg + k * 8;
    float sv[8] = {0.f, 0.f, 0.f, 0.f, 0.f, 0.f, 0.f, 0.f};
#pragma unroll
    for (int s = 0; s < SPLIT; ++s) {
      u16x8 v = *(const u16x8*)(Pp + ((size_t)s * NN + i) * HH + hc * 8);
#pragma unroll
      for (int e = 0; e < 8; ++e) sv[e] += bf2f(v[e]);
    }
    u16x8 xv;
#pragma unroll
    for (int e = 0; e < 8; ++e) {
      cs[e] += sv[e];
      xv[e] = f2bf(fmaxf(sv[e], 0.f));
    }
    int pos = scont ^ (i & 7);
    *(u16x8*)(xws + (((size_t)(b * 4 + dt)) * 512 + (i & 63) * 8 + pos) * 8) = xv;
  }
#pragma unroll
  for (int e = 0; e < 8; ++e) csm[rg][hc * 8 + e] = cs[e];
  __syncthreads();
  float v = 0.f;
#pragma unroll
  for (int r8 = 0; r8 < 8; ++r8) v += csm[r8][tid];
  atomicAdd(&fin[tid], v);
}

// reduce2: sum_s P[s] -> out2 fp32 + fused column-sum into fin[256..511]
__global__ void reduce2_kernel(const unsigned short* __restrict__ Pp,
                               float* __restrict__ outp,
                               float* __restrict__ fin)
{
  __shared__ float csm[8][256];
  const int tid = threadIdx.x;
  const int b   = blockIdx.x;
  const int hc  = tid & 31;
  const int rg  = tid >> 5;
  float cs[8] = {0.f, 0.f, 0.f, 0.f, 0.f, 0.f, 0.f, 0.f};
  for (int k = 0; k < 8; ++k) {
    int i = b * 64 + rg + k * 8;
    float sv[8] = {0.f, 0.f, 0.f, 0.f, 0.f, 0.f, 0.f, 0.f};
#pragma unroll
    for (int s = 0; s < SPLIT; ++s) {
      u16x8 v = *(const u16x8*)(Pp + ((size_t)s * NN + i) * HH + hc * 8);
#pragma unroll
      for (int e = 0; e < 8; ++e) sv[e] += bf2f(v[e]);
    }
    float* o = outp + (size_t)i * HH + hc * 8;
    *(f32x4*)o = (f32x4){sv[0], sv[1], sv[2], sv[3]};
    *(f32x4*)(o + 4) = (f32x4){sv[4], sv[5], sv[6], sv[7]};
#pragma unroll
    for (int e = 0; e < 8; ++e) cs[e] += sv[e];
  }
#pragma unroll
  for (int e = 0; e < 8; ++e) csm[rg][hc * 8 + e] = cs[e];
  __syncthreads();
  float v = 0.f;
#pragma unroll
  for (int r8 = 0; r8 < 8; ++r8) v += csm[r8][tid];
  atomicAdd(&fin[256 + tid], v);
}

__global__ void zero_fin_kernel(float* fin) {
  fin[blockIdx.x * 256 + threadIdx.x] = 0.f;
}

// ---------------------------------------------------------------------------
extern "C" void kernel_launch(void* const* d_in, const int* in_sizes, int n_in,
                              void* d_out, int out_size, void* d_ws, size_t ws_size,
                              hipStream_t stream)
{
  const float* adj = (const float*)d_in[0];
  const float* bw1 = (const float*)d_in[1];
  const float* bc1 = (const float*)d_in[2];
  const float* bw2 = (const float*)d_in[3];
  const float* bc2 = (const float*)d_in[4];
  float* out2 = (float*)d_out;                       // 6144*256 fp32
  float* fin  = (float*)d_out + (size_t)NN * HH;     // 512 fp32

  char* ws = (char*)d_ws;
  unsigned short* Pp   = (unsigned short*)(ws + 0);          // 25165824 B
  unsigned short* B1ws = (unsigned short*)(ws + 25165824);   //  6291456 B
  unsigned short* B2ws = (unsigned short*)(ws + 31457280);   //  6291456 B
  unsigned short* xws  = (unsigned short*)(ws + 37748736);   //  3145728 B
  unsigned short* w2ws = (unsigned short*)(ws + 40894464);   //   262144 B (end 41156608)

  zero_fin_kernel<<<2, 256, 0, stream>>>(fin);
  wgen_kernel<<<192, 256, 0, stream>>>(bw1, bc1, B1ws, 96, NN);
  gemm_adj_kernel<<<dim3(96, SPLIT), 256, 0, stream>>>(adj, B1ws, Pp);
  reduce1_kernel<<<96, 256, 0, stream>>>(Pp, xws, fin);
  wgen_kernel<<<8, 256, 0, stream>>>(bw2, bc2, w2ws, 4, HH);
  gemm_y_kernel<<<dim3(96, 2), 256, 0, stream>>>(xws, w2ws, B2ws);
  gemm_adj_kernel<<<dim3(96, SPLIT), 256, 0, stream>>>(adj, B2ws, Pp);
  reduce2_kernel<<<96, 256, 0, stream>>>(Pp, out2, fin);
}

// Round 5
// 197.231 us; speedup vs baseline: 1.1559x; 1.1559x over previous
//
#include <hip/hip_runtime.h>

// RGCN restructured:
//   out1 = A @ W1,   A[i, r*N+j] = adj[r,i,j]   (6144 x 12288) @ (12288 x 256)
//   out2 = A @ Y,    Y[r*N+j, h] = (relu(out1) @ W2_r)[j,h]
//   final[h] = sum_i out1[i,h] ; final[256+h] = sum_i out2[i,h]
// R5 = known-good R2 structure (single-buffer LDS, loads-before-compute,
// bf16 partials, fused reduces) + merged prep kernel + 2-deep A prefetch.

#define NN 6144
#define HH 256
#define SPLIT 8
#define KCHUNK 1536   // (2*NN)/SPLIT
#define KSTEPS 24     // KCHUNK/64

typedef __attribute__((ext_vector_type(4))) float f32x4;
typedef __attribute__((ext_vector_type(8))) unsigned short u16x8;
typedef __attribute__((ext_vector_type(4))) unsigned short u16x4;

__device__ __forceinline__ unsigned short f2bf(float f) {
  unsigned int u = __float_as_uint(f);
  u += 0x7FFFu + ((u >> 16) & 1u);   // RNE
  return (unsigned short)(u >> 16);
}
__device__ __forceinline__ float bf2f(unsigned short h) {
  return __uint_as_float(((unsigned int)h) << 16);
}

__device__ __forceinline__ void mfma_bf16(f32x4& d, u16x8 a, u16x8 b) {
  asm("v_mfma_f32_16x16x32_bf16 %0, %1, %2, %0" : "+v"(d) : "v"(a), "v"(b));
}

// ---------------------------------------------------------------------------
// prep: fused {zero fin} + {wgen W1: 192 tiles} + {wgen W2: 8 tiles}.
// wgen body is byte-identical to the validated R2 wgen:
// out[t*2048 + h*8 + sp] holds W[k = t*64 + (sp^(h&7))*8 + e][h]
// ---------------------------------------------------------------------------
__global__ void prep_kernel(const float* __restrict__ bw1, const float* __restrict__ bc1,
                            const float* __restrict__ bw2, const float* __restrict__ bc2,
                            unsigned short* __restrict__ B1ws, unsigned short* __restrict__ w2ws,
                            float* __restrict__ fin)
{
  const int b   = blockIdx.x;
  const int tid = threadIdx.x;
  if (b >= 200) { fin[(b - 200) * 256 + tid] = 0.f; return; }

  const float* basis; const float* bc; unsigned short* outw;
  int tilesPerR, jdim, t;
  if (b < 192) { basis = bw1; bc = bc1; outw = B1ws; tilesPerR = 96; jdim = NN; t = b; }
  else         { basis = bw2; bc = bc2; outw = w2ws; tilesPerR = 4;  jdim = HH; t = b - 192; }

  __shared__ unsigned short wt[64][265];
  const int r  = t / tilesPerR;
  const int jt = t % tilesPerR;
  const float c0 = bc[r * 2 + 0];
  const float c1 = bc[r * 2 + 1];
  const float* b0 = basis + (size_t)jt * 64 * HH;
  const float* b1 = basis + (size_t)jdim * HH + (size_t)jt * 64 * HH;
#pragma unroll
  for (int k = 0; k < 16; ++k) {
    int idx = tid + k * 256;
    int row = idx >> 6;
    int c4  = (idx & 63) * 4;
    f32x4 v0 = *(const f32x4*)(b0 + (size_t)row * HH + c4);
    f32x4 v1 = *(const f32x4*)(b1 + (size_t)row * HH + c4);
    wt[row][c4 + 0] = f2bf(c0 * v0.x + c1 * v1.x);
    wt[row][c4 + 1] = f2bf(c0 * v0.y + c1 * v1.y);
    wt[row][c4 + 2] = f2bf(c0 * v0.z + c1 * v1.z);
    wt[row][c4 + 3] = f2bf(c0 * v0.w + c1 * v1.w);
  }
  __syncthreads();
#pragma unroll
  for (int k = 0; k < 8; ++k) {
    int chunk = tid + k * 256;
    int h  = chunk >> 3;
    int sp = chunk & 7;
    int j0 = (sp ^ (h & 7)) * 8;
    u16x8 v;
#pragma unroll
    for (int e = 0; e < 8; ++e) v[e] = wt[j0 + e][h];
    *(u16x8*)(outw + ((size_t)t * 2048 + chunk) * 8) = v;
  }
}

// ---------------------------------------------------------------------------
// Main GEMM: P_bf16[s] = A_chunk @ B_chunk  (BM=64, BN=256, BK=64)
// R2 structure, plus 2-deep A register prefetch (av0/av1, unroll-2):
//   iter kk: sync; STAGE_A(av(kk)); STAGE_B(bv(kk)); sync;
//            ISSUE_B(kk+1); ISSUE_A(kk+2); COMPUTE
// ---------------------------------------------------------------------------
__global__ __launch_bounds__(256, 3) void gemm_adj_kernel(
    const float* __restrict__ adj, const unsigned short* __restrict__ Bws,
    unsigned short* __restrict__ Pp)
{
  __shared__ __align__(16) unsigned short Alds[64 * 64];
  __shared__ __align__(16) unsigned short Blds[256 * 64];
  const int tid  = threadIdx.x;
  const int lane = tid & 63;
  const int wave = tid >> 6;
  const int mb = blockIdx.x;
  const int s  = blockIdx.y;
  const int i0 = mb * 64;
  const int kbase = s * KCHUNK;
  const int rrel  = kbase / NN;
  const int jb    = kbase % NN;
  const int tBase = kbase / 64;

  const float* aRow = adj + (size_t)rrel * NN * NN
                      + (size_t)(i0 + (tid >> 4)) * NN + jb + (tid & 15) * 4;
  const unsigned short* bBase = Bws + (size_t)tBase * 2048 * 8 + (size_t)tid * 8;

  f32x4 acc[4][4];
#pragma unroll
  for (int m = 0; m < 4; ++m)
#pragma unroll
    for (int n = 0; n < 4; ++n) acc[m][n] = (f32x4){0.f, 0.f, 0.f, 0.f};

  f32x4 av0[4], av1[4];
  u16x8 bv[8];

#define ISSUE_A(SET, KK) do {                                                  \
    _Pragma("unroll")                                                          \
    for (int it = 0; it < 4; ++it)                                             \
      SET[it] = *(const f32x4*)(aRow + (size_t)it * 16 * NN + (KK) * 64);      \
  } while (0)

#define ISSUE_B(KK) do {                                                       \
    _Pragma("unroll")                                                          \
    for (int c = 0; c < 8; ++c)                                                \
      bv[c] = *(const u16x8*)(bBase + (size_t)(KK) * 2048 * 8 + c * 256 * 8);  \
  } while (0)

#define STAGE_A(SET) do {                                                      \
    _Pragma("unroll")                                                          \
    for (int it = 0; it < 4; ++it) {                                           \
      int row = (tid >> 4) + it * 16;                                          \
      int off = ((tid & 15) * 8) ^ ((row & 7) << 4);                           \
      u16x4 w;                                                                 \
      w[0] = f2bf(SET[it].x); w[1] = f2bf(SET[it].y);                          \
      w[2] = f2bf(SET[it].z); w[3] = f2bf(SET[it].w);                          \
      *(u16x4*)((char*)Alds + row * 128 + off) = w;                            \
    } } while (0)

#define STAGE_B() do {                                                         \
    _Pragma("unroll")                                                          \
    for (int c = 0; c < 8; ++c)                                                \
      *(u16x8*)(Blds + ((size_t)c * 256 + tid) * 8) = bv[c];                   \
  } while (0)

#define COMPUTE() do {                                                         \
    _Pragma("unroll")                                                          \
    for (int ks = 0; ks < 2; ++ks) {                                           \
      u16x8 af[4], bfr[4];                                                     \
      _Pragma("unroll")                                                        \
      for (int m = 0; m < 4; ++m) {                                            \
        int row = m * 16 + (lane & 15);                                        \
        int off = (ks * 64 + ((lane >> 4) << 4)) ^ ((row & 7) << 4);           \
        af[m] = *(const u16x8*)((const char*)Alds + row * 128 + off);          \
      }                                                                        \
      _Pragma("unroll")                                                        \
      for (int n = 0; n < 4; ++n) {                                            \
        int row = wave * 64 + n * 16 + (lane & 15);                            \
        int off = (ks * 64 + ((lane >> 4) << 4)) ^ ((row & 7) << 4);           \
        bfr[n] = *(const u16x8*)((const char*)Blds + row * 128 + off);         \
      }                                                                        \
      _Pragma("unroll")                                                        \
      for (int m = 0; m < 4; ++m)                                              \
        _Pragma("unroll")                                                      \
        for (int n = 0; n < 4; ++n)                                            \
          mfma_bf16(acc[m][n], af[m], bfr[n]);                                 \
    } } while (0)

  // prologue: A(0), B(0), A(1) in flight
  ISSUE_A(av0, 0);
  ISSUE_B(0);
  ISSUE_A(av1, 1);

  for (int kk = 0; kk < KSTEPS; kk += 2) {
    // ---- iter kk (even): stage av0 ----
    __syncthreads();
    STAGE_A(av0);
    STAGE_B();
    __syncthreads();
    ISSUE_B(kk + 1);                        // kk+1 <= 23 always (kk even < 24)
    if (kk + 2 < KSTEPS) ISSUE_A(av0, kk + 2);
    COMPUTE();
    // ---- iter kk+1 (odd): stage av1 ----
    __syncthreads();
    STAGE_A(av1);
    STAGE_B();
    __syncthreads();
    if (kk + 2 < KSTEPS) ISSUE_B(kk + 2);
    if (kk + 3 < KSTEPS) ISSUE_A(av1, kk + 3);
    COMPUTE();
  }
#undef ISSUE_A
#undef ISSUE_B
#undef STAGE_A
#undef STAGE_B
#undef COMPUTE

  // partials bf16: P[s][i][h]   (C/D: col=lane&15, row=(lane>>4)*4+q)
  unsigned short* P = Pp + ((size_t)s * NN + i0) * HH;
#pragma unroll
  for (int m = 0; m < 4; ++m)
#pragma unroll
    for (int n = 0; n < 4; ++n) {
      int col = wave * 64 + n * 16 + (lane & 15);
#pragma unroll
      for (int q = 0; q < 4; ++q) {
        int row = m * 16 + ((lane >> 4) << 2) + q;
        P[(size_t)row * HH + col] = f2bf(acc[m][n][q]);
      }
    }
}

// ---------------------------------------------------------------------------
// gemm_y: Y_r = x @ W2_r (K=256). Output written in B-operand layout.
// (verbatim from the validated R2 kernel)
// ---------------------------------------------------------------------------
__global__ __launch_bounds__(256, 2) void gemm_y_kernel(
    const unsigned short* __restrict__ xws, const unsigned short* __restrict__ w2ws,
    unsigned short* __restrict__ B2ws)
{
  __shared__ __align__(16) unsigned short Alds[64 * 64];
  __shared__ __align__(16) unsigned short Blds[256 * 64];
  const int tid  = threadIdx.x;
  const int lane = tid & 63;
  const int wave = tid >> 6;
  const int mb = blockIdx.x;
  const int r  = blockIdx.y;

  f32x4 acc[4][4];
#pragma unroll
  for (int m = 0; m < 4; ++m)
#pragma unroll
    for (int n = 0; n < 4; ++n) acc[m][n] = (f32x4){0.f, 0.f, 0.f, 0.f};

  for (int dt = 0; dt < 4; ++dt) {
    u16x8 avv[2];
    avv[0] = *(const u16x8*)(xws + (((size_t)(mb * 4 + dt)) * 512 + tid) * 8);
    avv[1] = *(const u16x8*)(xws + (((size_t)(mb * 4 + dt)) * 512 + 256 + tid) * 8);
    u16x8 bv[8];
#pragma unroll
    for (int c = 0; c < 8; ++c)
      bv[c] = *(const u16x8*)(w2ws + (((size_t)(r * 4 + dt)) * 2048 + c * 256 + tid) * 8);
    __syncthreads();
    *(u16x8*)(Alds + (size_t)tid * 8) = avv[0];
    *(u16x8*)(Alds + ((size_t)256 + tid) * 8) = avv[1];
#pragma unroll
    for (int c = 0; c < 8; ++c)
      *(u16x8*)(Blds + ((size_t)c * 256 + tid) * 8) = bv[c];
    __syncthreads();
#pragma unroll
    for (int ks = 0; ks < 2; ++ks) {
      u16x8 af[4], bfr[4];
#pragma unroll
      for (int m = 0; m < 4; ++m) {
        int row = m * 16 + (lane & 15);
        int off = (ks * 64 + ((lane >> 4) << 4)) ^ ((row & 7) << 4);
        af[m] = *(const u16x8*)((const char*)Alds + row * 128 + off);
      }
#pragma unroll
      for (int n = 0; n < 4; ++n) {
        int row = wave * 64 + n * 16 + (lane & 15);
        int off = (ks * 64 + ((lane >> 4) << 4)) ^ ((row & 7) << 4);
        bfr[n] = *(const u16x8*)((const char*)Blds + row * 128 + off);
      }
#pragma unroll
      for (int m = 0; m < 4; ++m)
#pragma unroll
        for (int n = 0; n < 4; ++n)
          mfma_bf16(acc[m][n], af[m], bfr[n]);
    }
  }
  // emit Y in B-operand layout: chunk(t=r*96+mb, h, pos) gets k-slot pos^(h&7)
  const int tg = r * 96 + mb;
#pragma unroll
  for (int m = 0; m < 4; ++m) {
    int scont = m * 2 + ((lane >> 4) >> 1);
    int e0    = ((lane >> 4) & 1) * 4;
#pragma unroll
    for (int n = 0; n < 4; ++n) {
      int h   = wave * 64 + n * 16 + (lane & 15);
      int pos = scont ^ (h & 7);
      u16x4 v;
      v[0] = f2bf(acc[m][n][0]); v[1] = f2bf(acc[m][n][1]);
      v[2] = f2bf(acc[m][n][2]); v[3] = f2bf(acc[m][n][3]);
      *(u16x4*)(B2ws + (((size_t)tg * 2048 + h * 8 + pos) * 8 + e0)) = v;
    }
  }
}

// ---------------------------------------------------------------------------
// reduce1: sum_s P[s] -> x = relu -> bf16 pre-swizzled A-tiles (xws)
//          + fused column-sum of out1 into fin[0..255]
// ---------------------------------------------------------------------------
__global__ void reduce1_kernel(const unsigned short* __restrict__ Pp,
                               unsigned short* __restrict__ xws,
                               float* __restrict__ fin)
{
  __shared__ float csm[8][256];
  const int tid = threadIdx.x;
  const int b   = blockIdx.x;
  const int hc  = tid & 31;
  const int rg  = tid >> 5;
  const int dt    = hc >> 3;
  const int scont = hc & 7;
  float cs[8] = {0.f, 0.f, 0.f, 0.f, 0.f, 0.f, 0.f, 0.f};
  for (int k = 0; k < 8; ++k) {
    int i = b * 64 + rg + k * 8;
    float sv[8] = {0.f, 0.f, 0.f, 0.f, 0.f, 0.f, 0.f, 0.f};
#pragma unroll
    for (int s = 0; s < SPLIT; ++s) {
      u16x8 v = *(const u16x8*)(Pp + ((size_t)s * NN + i) * HH + hc * 8);
#pragma unroll
      for (int e = 0; e < 8; ++e) sv[e] += bf2f(v[e]);
    }
    u16x8 xv;
#pragma unroll
    for (int e = 0; e < 8; ++e) {
      cs[e] += sv[e];
      xv[e] = f2bf(fmaxf(sv[e], 0.f));
    }
    int pos = scont ^ (i & 7);
    *(u16x8*)(xws + (((size_t)(b * 4 + dt)) * 512 + (i & 63) * 8 + pos) * 8) = xv;
  }
#pragma unroll
  for (int e = 0; e < 8; ++e) csm[rg][hc * 8 + e] = cs[e];
  __syncthreads();
  float v = 0.f;
#pragma unroll
  for (int r8 = 0; r8 < 8; ++r8) v += csm[r8][tid];
  atomicAdd(&fin[tid], v);
}

// reduce2: sum_s P[s] -> out2 fp32 + fused column-sum into fin[256..511]
__global__ void reduce2_kernel(const unsigned short* __restrict__ Pp,
                               float* __restrict__ outp,
                               float* __restrict__ fin)
{
  __shared__ float csm[8][256];
  const int tid = threadIdx.x;
  const int b   = blockIdx.x;
  const int hc  = tid & 31;
  const int rg  = tid >> 5;
  float cs[8] = {0.f, 0.f, 0.f, 0.f, 0.f, 0.f, 0.f, 0.f};
  for (int k = 0; k < 8; ++k) {
    int i = b * 64 + rg + k * 8;
    float sv[8] = {0.f, 0.f, 0.f, 0.f, 0.f, 0.f, 0.f, 0.f};
#pragma unroll
    for (int s = 0; s < SPLIT; ++s) {
      u16x8 v = *(const u16x8*)(Pp + ((size_t)s * NN + i) * HH + hc * 8);
#pragma unroll
      for (int e = 0; e < 8; ++e) sv[e] += bf2f(v[e]);
    }
    float* o = outp + (size_t)i * HH + hc * 8;
    *(f32x4*)o = (f32x4){sv[0], sv[1], sv[2], sv[3]};
    *(f32x4*)(o + 4) = (f32x4){sv[4], sv[5], sv[6], sv[7]};
#pragma unroll
    for (int e = 0; e < 8; ++e) cs[e] += sv[e];
  }
#pragma unroll
  for (int e = 0; e < 8; ++e) csm[rg][hc * 8 + e] = cs[e];
  __syncthreads();
  float v = 0.f;
#pragma unroll
  for (int r8 = 0; r8 < 8; ++r8) v += csm[r8][tid];
  atomicAdd(&fin[256 + tid], v);
}

// ---------------------------------------------------------------------------
extern "C" void kernel_launch(void* const* d_in, const int* in_sizes, int n_in,
                              void* d_out, int out_size, void* d_ws, size_t ws_size,
                              hipStream_t stream)
{
  const float* adj = (const float*)d_in[0];
  const float* bw1 = (const float*)d_in[1];
  const float* bc1 = (const float*)d_in[2];
  const float* bw2 = (const float*)d_in[3];
  const float* bc2 = (const float*)d_in[4];
  float* out2 = (float*)d_out;                       // 6144*256 fp32
  float* fin  = (float*)d_out + (size_t)NN * HH;     // 512 fp32

  char* ws = (char*)d_ws;
  unsigned short* Pp   = (unsigned short*)(ws + 0);          // 25165824 B
  unsigned short* B1ws = (unsigned short*)(ws + 25165824);   //  6291456 B
  unsigned short* B2ws = (unsigned short*)(ws + 31457280);   //  6291456 B
  unsigned short* xws  = (unsigned short*)(ws + 37748736);   //  3145728 B
  unsigned short* w2ws = (unsigned short*)(ws + 40894464);   //   262144 B (end 41156608)

  prep_kernel<<<202, 256, 0, stream>>>(bw1, bc1, bw2, bc2, B1ws, w2ws, fin);
  gemm_adj_kernel<<<dim3(96, SPLIT), 256, 0, stream>>>(adj, B1ws, Pp);
  reduce1_kernel<<<96, 256, 0, stream>>>(Pp, xws, fin);
  gemm_y_kernel<<<dim3(96, 2), 256, 0, stream>>>(xws, w2ws, B2ws);
  gemm_adj_kernel<<<dim3(96, SPLIT), 256, 0, stream>>>(adj, B2ws, Pp);
  reduce2_kernel<<<96, 256, 0, stream>>>(Pp, out2, fin);
}